// Round 7
// baseline (216.942 us; speedup 1.0000x reference)
//
#include <hip/hip_runtime.h>
#include <stdint.h>

// Problem constants (reference setup_inputs: N=4096, D=256, C=1000)
#define NR 4096
#define DD 256
#define NC_TOT 4096000
#define TILES 32
#define NTRI 528
#define NBLK_GRAM (3 * NTRI)

typedef float f32x4 __attribute__((ext_vector_type(4)));
typedef unsigned short u16;
typedef unsigned char u8;

// ws layout:
//   [0,16)                   u32 gram-completion counter (zeroed by prep)
//   [256,  +2048*4)          mse per-block partials
//   [16384, +1584*4)         gram per-block partials
//   [32768, +6*4096*4)       fp32 row sq-norms (exact, from fp32 input)
//   [131072, +6*4096*256)    fp8 e4m3 feature data, CHUNK-MAJOR (BK=64):
//     [mat(6)][panel(32)][kc2(4)][row(128)][col(64)] -- 8 KB contiguous chunks
#define WS_MSEP_OFF  256
#define WS_FEATP_OFF 16384
#define WS_SQN_OFF   32768
#define WS_FP8_OFF   131072

// ---------------- prep (fp32->fp8 chunked + row norms) + label-MSE --------
// fp8 stores are NONTEMPORAL: lines land clean in memory, so gram's reads
// are serviced as normal L3/HBM fills instead of cross-XCD dirty-L2 hits.
__global__ __launch_bounds__(256) void prep_mse_kernel(
    const float* __restrict__ m0, const float* __restrict__ m1,
    const float* __restrict__ m2, const float* __restrict__ m3,
    const float* __restrict__ m4, const float* __restrict__ m5,
    const float4* __restrict__ pred, const float4* __restrict__ target,
    u8* __restrict__ q8, float* __restrict__ sqn, float* __restrict__ msep,
    unsigned* __restrict__ cnt)
{
    __shared__ float sr[4];
    const int t = threadIdx.x, w = t >> 6, lane = t & 63;
    const int y = blockIdx.y;
    if (y == 0 && blockIdx.x == 0 && t == 0) *cnt = 0u;

    if (y < 6) {
        const float* mp = m0;
        if (y == 1) mp = m1;
        else if (y == 2) mp = m2;
        else if (y == 3) mp = m3;
        else if (y == 4) mp = m4;
        else if (y == 5) mp = m5;
        const int R = blockIdx.x * 4 + w;            // global row 0..4095
        const int P = R >> 7, rr = R & 127;          // panel, row-in-panel
        const float4* src = (const float4*)(mp + (size_t)R * DD);
        float4 v = src[lane];
        float ss = v.x * v.x + v.y * v.y + v.z * v.z + v.w * v.w;
        unsigned lo = __builtin_amdgcn_cvt_pk_fp8_f32(v.x, v.y, 0u, false);
        unsigned hi = __builtin_amdgcn_cvt_pk_fp8_f32(v.z, v.w, 0u, false);
        unsigned packed = (lo & 0xffffu) | (hi << 16);
        // BK=64 chunk-major: lane covers cols 4l..4l+3 -> kc2 = l>>4
        size_t idx = ((size_t)((y * 32 + P) * 4 + (lane >> 4)) << 13)
                     + rr * 64 + (lane & 15) * 4;    // bytes
        __builtin_nontemporal_store(packed, (unsigned*)(q8 + idx));
        #pragma unroll
        for (int off = 32; off; off >>= 1) ss += __shfl_down(ss, off);
        if (lane == 0) sqn[(size_t)y * NR + R] = ss;
    } else {
        const int b2 = (y - 6) * 1024 + blockIdx.x;   // 2048 mse blocks
        float s = 0.f;
        for (int i = b2 * 256 + t; i < NC_TOT / 4; i += 2048 * 256) {
            float4 x = pred[i], yv = target[i];
            float dx = x.x - yv.x, dy = x.y - yv.y;
            float dz = x.z - yv.z, dw = x.w - yv.w;
            s += dx * dx + dy * dy + dz * dz + dw * dw;
        }
        #pragma unroll
        for (int off = 32; off; off >>= 1) s += __shfl_down(s, off);
        if (lane == 0) sr[w] = s;
        __syncthreads();
        if (t == 0) msep[b2] = sr[0] + sr[1] + sr[2] + sr[3];
    }
}

// ---------------- epilogue, diagonal handling templated -------------------
template <bool DIAG>
__device__ __forceinline__ float epilogue(
    const f32x4 accp[4][4], const f32x4 acct[4][4],
    const float s_sqn[4][128], int wm, int wn, int quad, int l16)
{
    float local = 0.f;
    #pragma unroll
    for (int mi = 0; mi < 4; mi++) {
        const int i0 = wm * 64 + mi * 16 + quad * 4;
        const f32x4 sip = *(const f32x4*)&s_sqn[0][i0];
        const f32x4 sit = *(const f32x4*)&s_sqn[2][i0];
        #pragma unroll
        for (int ni = 0; ni < 4; ni++) {
            const int j_loc = wn * 64 + ni * 16 + l16;
            const float spj = s_sqn[1][j_loc], stj = s_sqn[3][j_loc];
            const f32x4 gp = accp[mi][ni], gt = acct[mi][ni];
            #pragma unroll
            for (int r = 0; r < 4; r++) {
                float dp2 = fmaf(-2.f, gp[r], sip[r] + spj);
                float dt2 = fmaf(-2.f, gt[r], sit[r] + stj);
                float dp = __builtin_amdgcn_sqrtf(fmaxf(dp2, 0.f));
                float dt = __builtin_amdgcn_sqrtf(fmaxf(dt2, 0.f));
                if (DIAG) {
                    if (i0 + r == j_loc) { dp = 0.f; dt = 0.f; }
                }
                float d = dp - dt;
                local = fmaf(d, d, local);
            }
        }
    }
    return local;
}

// ---------------- fused fp8 Gram + pairwise-L2 + MSE, triangular tiles ----
// BK=64: 4 K-iterations per block (half the vmcnt drains), 8 glds in flight
// per wave per iteration, 64 MFMA/wave/iter. LDS 32 KB tiles.
__global__ __launch_bounds__(256) void gram_loss_kernel(
    const u8* __restrict__ q8, const float* __restrict__ sqn,
    float* __restrict__ featp, const float* __restrict__ msep,
    unsigned* __restrict__ cnt, float* __restrict__ out)
{
    __shared__ u8 tile[4][8192];       // Ap, Bp, At, Bt: 8 KB fp8 chunks
    __shared__ float s_sqn[4][128];
    __shared__ float s_red[8];
    __shared__ int s_last;

    const int f = blockIdx.y;
    int ti = 0, rem = blockIdx.x;
    while (rem >= TILES - ti) { rem -= TILES - ti; ti++; }
    const int tj = ti + rem;

    const int t = threadIdx.x;
    const int w = t >> 6, lane = t & 63;
    const int wm = w >> 1, wn = w & 1;        // 2x2 waves, 64x64 each
    const int quad = lane >> 4, l16 = lane & 15;

    const float* sqp = sqn + (size_t)f * NR;
    const float* sqt = sqn + (size_t)(3 + f) * NR;
    for (int i = t; i < 512; i += 256) {
        int which = i >> 7, r = i & 127;
        const float* sp = (which < 2) ? sqp : sqt;
        int trow = (which & 1) ? tj : ti;
        s_sqn[which][r] = sp[trow * 128 + r];
    }

    // byte offsets of chunk kc2=0 for the 4 (mat, panel) combos (8 KB chunks)
    const char* qb = (const char*)q8;
    size_t cbase[4];
    cbase[0] = ((size_t)(f * 32 + ti) * 4) << 13;
    cbase[1] = ((size_t)(f * 32 + tj) * 4) << 13;
    cbase[2] = ((size_t)((3 + f) * 32 + ti) * 4) << 13;
    cbase[3] = ((size_t)((3 + f) * 32 + tj) * 4) << 13;

    f32x4 accp[4][4], acct[4][4];
    #pragma unroll
    for (int a = 0; a < 4; a++)
        #pragma unroll
        for (int bb = 0; bb < 4; bb++) {
            accp[a][bb] = f32x4{0.f, 0.f, 0.f, 0.f};
            acct[a][bb] = f32x4{0.f, 0.f, 0.f, 0.f};
        }

    for (int kc = 0; kc < 4; kc++) {
        // ---- stage: 4 chunks x 8 KB; each wave copies 2 contiguous 1 KB
        #pragma unroll
        for (int m = 0; m < 4; m++) {
            const char* gsrc = qb + cbase[m] + ((size_t)kc << 13) + t * 16;
            char* ldst = (char*)&tile[m][0] + w * 1024;   // wave-uniform base
            __builtin_amdgcn_global_load_lds(
                (const __attribute__((address_space(1))) void*)gsrc,
                (__attribute__((address_space(3))) void*)ldst, 16, 0, 0);
            __builtin_amdgcn_global_load_lds(
                (const __attribute__((address_space(1))) void*)(gsrc + 4096),
                (__attribute__((address_space(3))) void*)(ldst + 4096), 16, 0, 0);
        }
        __syncthreads();

        #pragma unroll
        for (int kg = 0; kg < 2; kg++) {           // two K=32 granules
            const int colo = kg * 32 + quad * 8;   // byte offset in 64 B row
            long afr[4], bfr[4];
            #pragma unroll
            for (int mi = 0; mi < 4; mi++)
                afr[mi] = *(const long*)&tile[0][(wm * 64 + mi * 16 + l16) * 64 + colo];
            #pragma unroll
            for (int ni = 0; ni < 4; ni++)
                bfr[ni] = *(const long*)&tile[1][(wn * 64 + ni * 16 + l16) * 64 + colo];
            #pragma unroll
            for (int mi = 0; mi < 4; mi++)
                #pragma unroll
                for (int ni = 0; ni < 4; ni++)
                    accp[mi][ni] = __builtin_amdgcn_mfma_f32_16x16x32_fp8_fp8(
                        afr[mi], bfr[ni], accp[mi][ni], 0, 0, 0);
            #pragma unroll
            for (int mi = 0; mi < 4; mi++)
                afr[mi] = *(const long*)&tile[2][(wm * 64 + mi * 16 + l16) * 64 + colo];
            #pragma unroll
            for (int ni = 0; ni < 4; ni++)
                bfr[ni] = *(const long*)&tile[3][(wn * 64 + ni * 16 + l16) * 64 + colo];
            #pragma unroll
            for (int mi = 0; mi < 4; mi++)
                #pragma unroll
                for (int ni = 0; ni < 4; ni++)
                    acct[mi][ni] = __builtin_amdgcn_mfma_f32_16x16x32_fp8_fp8(
                        afr[mi], bfr[ni], acct[mi][ni], 0, 0, 0);
        }
        __syncthreads();
    }

    float local = (ti == tj)
        ? epilogue<true >(accp, acct, s_sqn, wm, wn, quad, l16)
        : epilogue<false>(accp, acct, s_sqn, wm, wn, quad, l16);

    #pragma unroll
    for (int off = 32; off; off >>= 1) local += __shfl_down(local, off);
    if (lane == 0) s_red[w] = local;
    __syncthreads();
    if (t == 0) {
        float bs = s_red[0] + s_red[1] + s_red[2] + s_red[3];
        featp[f * NTRI + blockIdx.x] = (ti == tj) ? bs : 2.f * bs;
        __threadfence();
        unsigned old = atomicAdd(cnt, 1u);
        s_last = (old == NBLK_GRAM - 1) ? 1 : 0;
    }
    __syncthreads();

    if (s_last) {                       // last block: global combine
        __threadfence();
        float s = 0.f, m = 0.f;
        for (int i = t; i < NBLK_GRAM; i += 256) s += featp[i];
        for (int i = t; i < 2048; i += 256) m += msep[i];
        #pragma unroll
        for (int off = 32; off; off >>= 1) {
            s += __shfl_down(s, off);
            m += __shfl_down(m, off);
        }
        if (lane == 0) { s_red[w] = s; s_red[4 + w] = m; }
        __syncthreads();
        if (t == 0) {
            float fs = s_red[0] + s_red[1] + s_red[2] + s_red[3];
            float ms = s_red[4] + s_red[5] + s_red[6] + s_red[7];
            out[0] = 0.2f * (ms / (float)NC_TOT) +
                     (0.8f / 3.0f) * (fs / ((float)NR * (float)NR));
        }
    }
}

extern "C" void kernel_launch(void* const* d_in, const int* in_sizes, int n_in,
                              void* d_out, int out_size, void* d_ws, size_t ws_size,
                              hipStream_t stream) {
    unsigned* cnt  = (unsigned*)d_ws;
    float* msep    = (float*)((char*)d_ws + WS_MSEP_OFF);
    float* featp   = (float*)((char*)d_ws + WS_FEATP_OFF);
    float* sqn     = (float*)((char*)d_ws + WS_SQN_OFF);
    u8* q8         = (u8*)((char*)d_ws + WS_FP8_OFF);

    prep_mse_kernel<<<dim3(1024, 8), 256, 0, stream>>>(
        (const float*)d_in[2], (const float*)d_in[3], (const float*)d_in[4],
        (const float*)d_in[5], (const float*)d_in[6], (const float*)d_in[7],
        (const float4*)d_in[0], (const float4*)d_in[1], q8, sqn, msep, cnt);

    gram_loss_kernel<<<dim3(NTRI, 3), 256, 0, stream>>>(
        q8, sqn, featp, msep, cnt, (float*)d_out);
}

// Round 8
// 161.699 us; speedup vs baseline: 1.3416x; 1.3416x over previous
//
#include <hip/hip_runtime.h>
#include <stdint.h>

// Problem constants (reference setup_inputs: N=4096, D=256, C=1000)
#define NR 4096
#define DD 256
#define NC_TOT 4096000
#define TILES 32
#define NTRI 528
#define NBLK_GRAM (3 * NTRI)

typedef float f32x4 __attribute__((ext_vector_type(4)));
typedef unsigned char u8;

// ws layout:
//   [0,16)                   u32 gram-completion counter (zeroed by prep)
//   [256,  +2048*4)          mse per-block partials
//   [16384, +1584*4)         gram per-block partials
//   [32768, +6*4096*4)       fp32 row sq-norms (exact, from fp32 input)
//   [131072, +6*4096*256)    fp8 e4m3 features, PANEL-major, granule-major:
//     [mat(6)][panel(32)] -> 32 KB contiguous panel laid out as
//     [g(32)][row(128)][8B]  where g = col/8  (identity with LDS layout)
#define WS_MSEP_OFF  256
#define WS_FEATP_OFF 16384
#define WS_SQN_OFF   32768
#define WS_FP8_OFF   131072

// ---------------- prep (fp32->fp8 granule-major + row norms) + label-MSE --
__global__ __launch_bounds__(256) void prep_mse_kernel(
    const float* __restrict__ m0, const float* __restrict__ m1,
    const float* __restrict__ m2, const float* __restrict__ m3,
    const float* __restrict__ m4, const float* __restrict__ m5,
    const float4* __restrict__ pred, const float4* __restrict__ target,
    u8* __restrict__ q8, float* __restrict__ sqn, float* __restrict__ msep,
    unsigned* __restrict__ cnt)
{
    __shared__ float sr[4];
    const int t = threadIdx.x, w = t >> 6, lane = t & 63;
    const int y = blockIdx.y;
    if (y == 0 && blockIdx.x == 0 && t == 0) *cnt = 0u;

    if (y < 6) {
        const float* mp = m0;
        if (y == 1) mp = m1;
        else if (y == 2) mp = m2;
        else if (y == 3) mp = m3;
        else if (y == 4) mp = m4;
        else if (y == 5) mp = m5;
        const int R = blockIdx.x * 4 + w;            // global row 0..4095
        const int P = R >> 7, rr = R & 127;          // panel, row-in-panel
        const float4* src = (const float4*)(mp + (size_t)R * DD);
        float4 v = src[lane];                        // cols 4*lane .. 4*lane+3
        float ss = v.x * v.x + v.y 
* v.y + v.z * v.z + v.w * v.w;
        unsigned lo = __builtin_amdgcn_cvt_pk_fp8_f32(v.x, v.y, 0u, false);
        unsigned hi = __builtin_amdgcn_cvt_pk_fp8_f32(v.z, v.w, 0u, false);
        unsigned packed = (lo & 0xffffu) | (hi << 16);
        // granule-major: col c -> g=c/8, byte c%8. Lane covers c=4l..4l+3:
        // g = l>>1, byte = (l&1)*4
        size_t idx = ((size_t)(y * 32 + P) << 15)
                     + (size_t)(lane >> 1) * 1024 + rr * 8 + (lane & 1) * 4;
        *(unsigned*)(q8 + idx) = packed;
        #pragma unroll
        for (int off = 32; off; off >>= 1) ss += __shfl_down(ss, off);
        if (lane == 0) sqn[(size_t)y * NR + R] = ss;
    } else {
        const int b2 = (y - 6) * 1024 + blockIdx.x;   // 2048 mse blocks
        float s = 0.f;
        for (int i = b2 * 256 + t; i < NC_TOT / 4; i += 2048 * 256) {
            float4 x = pred[i], yv = target[i];
            float dx = x.x - yv.x, dy = x.y - yv.y;
            float dz = x.z - yv.z, dw = x.w - yv.w;
            s += dx * dx + dy * dy + dz * dz + dw * dw;
        }
        #pragma unroll
        for (int off = 32; off; off >>= 1) s += __shfl_down(s, off);
        if (lane == 0) sr[w] = s;
        __syncthreads();
        if (t == 0) msep[b2] = sr[0] + sr[1] + sr[2] + sr[3];
    }
}

// ---------------- one full-K Gram accumulation from staged LDS panels -----
// LDS panel layout [g(32)][row(128)][8B]: ds_read lanes stride 8 B = 2 banks
// -> 16 lanes cover all 32 banks, 4 quads alias 2/bank = conflict-free.
__device__ __forceinline__ void gram_phase(
    f32x4 acc[4][4], const u8* tA, const u8* tB,
    int wm, int wn, int quad, int l16)
{
    #pragma unroll
    for (int kc = 0; kc < 8; kc++) {
        const int gg = kc * 4 + quad;
        long a[4], b[4];
        #pragma unroll
        for (int mi = 0; mi < 4; mi++)
            a[mi] = *(const long*)&tA[gg * 1024 + (wm * 64 + mi * 16 + l16) * 8];
        #pragma unroll
        for (int ni = 0; ni < 4; ni++)
            b[ni] = *(const long*)&tB[gg * 1024 + (wn * 64 + ni * 16 + l16) * 8];
        #pragma unroll
        for (int mi = 0; mi < 4; mi++)
            #pragma unroll
            for (int ni = 0; ni < 4; ni++)
                acc[mi][ni] = __builtin_amdgcn_mfma_f32_16x16x32_fp8_fp8(
                    a[mi], b[ni], acc[mi][ni], 0, 0, 0);
    }
}

// ---------------- epilogue, diagonal handling templated -------------------
template <bool DIAG>
__device__ __forceinline__ float epilogue(
    const f32x4 accp[4][4], const f32x4 acct[4][4],
    const float s_sqn[4][128], int wm, int wn, int quad, int l16)
{
    float local = 0.f;
    #pragma unroll
    for (int mi = 0; mi < 4; mi++) {
        const int i0 = wm * 64 + mi * 16 + quad * 4;
        const f32x4 sip = *(const f32x4*)&s_sqn[0][i0];
        const f32x4 sit = *(const f32x4*)&s_sqn[2][i0];
        #pragma unroll
        for (int ni = 0; ni < 4; ni++) {
            const int j_loc = wn * 64 + ni * 16 + l16;
            const float spj = s_sqn[1][j_loc], stj = s_sqn[3][j_loc];
            const f32x4 gp = accp[mi][ni], gt = acct[mi][ni];
            #pragma unroll
            for (int r = 0; r < 4; r++) {
                float dp2 = fmaf(-2.f, gp[r], sip[r] + spj);
                float dt2 = fmaf(-2.f, gt[r], sit[r] + stj);
                float dp = __builtin_amdgcn_sqrtf(fmaxf(dp2, 0.f));
                float dt = __builtin_amdgcn_sqrtf(fmaxf(dt2, 0.f));
                if (DIAG) {
                    if (i0 + r == j_loc) { dp = 0.f; dt = 0.f; }
                }
                float d = dp - dt;
                local = fmaf(d, d, local);
            }
        }
    }
    return local;
}

// ---------------- fused fp8 Gram + pairwise-L2 + MSE, triangular tiles ----
// Whole-K staging in two 64 KB phases (pred pair, target pair): 2 vmcnt
// drains per block instead of 8. ~66 KB LDS -> 2 blocks/CU co-resident to
// overlap each other's drains.
__global__ __launch_bounds__(256) void gram_loss_kernel(
    const u8* __restrict__ q8, const float* __restrict__ sqn,
    float* __restrict__ featp, const float* __restrict__ msep,
    unsigned* __restrict__ cnt, float* __restrict__ out)
{
    __shared__ u8 tileA[32768];        // full-K 128-row panel (A side)
    __shared__ u8 tileB[32768];        // full-K 128-row panel (B side)
    __shared__ float s_sqn[4][128];
    __shared__ float s_red[8];
    __shared__ int s_last;

    const int f = blockIdx.y;
    int ti = 0, rem = blockIdx.x;
    while (rem >= TILES - ti) { rem -= TILES - ti; ti++; }
    const int tj = ti + rem;

    const int t = threadIdx.x;
    const int w = t >> 6, lane = t & 63;
    const int wm = w >> 1, wn = w & 1;        // 2x2 waves, 64x64 each
    const int quad = lane >> 4, l16 = lane & 15;

    const float* sqp = sqn + (size_t)f * NR;
    const float* sqt = sqn + (size_t)(3 + f) * NR;
    for (int i = t; i < 512; i += 256) {
        int which = i >> 7, r = i & 127;
        const float* sp = (which < 2) ? sqp : sqt;
        int trow = (which & 1) ? tj : ti;
        s_sqn[which][r] = sp[trow * 128 + r];
    }

    const char* qb = (const char*)q8;
    const size_t pA = ((size_t)(f * 32 + ti)) << 15;
    const size_t pB = ((size_t)(f * 32 + tj)) << 15;
    const size_t tA_ = ((size_t)((3 + f) * 32 + ti)) << 15;
    const size_t tB_ = ((size_t)((3 + f) * 32 + tj)) << 15;

    // stage one 64 KB pair (two 32 KB panels); identity copy, 1 KB per glds
    auto stage2 = [&](size_t bA, size_t bB) {
        const char* gA = qb + bA + w * 8192 + lane * 16;
        const char* gB = qb + bB + w * 8192 + lane * 16;
        char* lA = (char*)tileA + w * 8192;
        char* lB = (char*)tileB + w * 8192;
        #pragma unroll
        for (int i = 0; i < 8; i++) {
            __builtin_amdgcn_global_load_lds(
                (const __attribute__((address_space(1))) void*)(gA + i * 1024),
                (__attribute__((address_space(3))) void*)(lA + i * 1024), 16, 0, 0);
            __builtin_amdgcn_global_load_lds(
                (const __attribute__((address_space(1))) void*)(gB + i * 1024),
                (__attribute__((address_space(3))) void*)(lB + i * 1024), 16, 0, 0);
        }
    };

    f32x4 accp[4][4], acct[4][4];
    #pragma unroll
    for (int a = 0; a < 4; a++)
        #pragma unroll
        for (int bb = 0; bb < 4; bb++) {
            accp[a][bb] = f32x4{0.f, 0.f, 0.f, 0.f};
            acct[a][bb] = f32x4{0.f, 0.f, 0.f, 0.f};
        }

    stage2(pA, pB);                    // pred pair
    __syncthreads();                   // drain 1
    gram_phase(accp, tileA, tileB, wm, wn, quad, l16);
    __syncthreads();                   // readers done before overwrite
    stage2(tA_, tB_);                  // target pair
    __syncthreads();                   // drain 2
    gram_phase(acct, tileA, tileB, wm, wn, quad, l16);

    float local = (ti == tj)
        ? epilogue<true >(accp, acct, s_sqn, wm, wn, quad, l16)
        : epilogue<false>(accp, acct, s_sqn, wm, wn, quad, l16);

    #pragma unroll
    for (int off = 32; off; off >>= 1) local += __shfl_down(local, off);
    if (lane == 0) s_red[w] = local;
    __syncthreads();
    if (t == 0) {
        float bs = s_red[0] + s_red[1] + s_red[2] + s_red[3];
        featp[f * NTRI + blockIdx.x] = (ti == tj) ? bs : 2.f * bs;
        __threadfence();
        unsigned old = atomicAdd(cnt, 1u);
        s_last = (old == NBLK_GRAM - 1) ? 1 : 0;
    }
    __syncthreads();

    if (s_last) {                       // last block: global combine
        __threadfence();
        float s = 0.f, m = 0.f;
        for (int i = t; i < NBLK_GRAM; i += 256) s += featp[i];
        for (int i = t; i < 2048; i += 256) m += msep[i];
        #pragma unroll
        for (int off = 32; off; off >>= 1) {
            s += __shfl_down(s, off);
            m += __shfl_down(m, off);
        }
        if (lane == 0) { s_red[w] = s; s_red[4 + w] = m; }
        __syncthreads();
        if (t == 0) {
            float fs = s_red[0] + s_red[1] + s_red[2] + s_red[3];
            float ms = s_red[4] + s_red[5] + s_red[6] + s_red[7];
            out[0] = 0.2f * (ms / (float)NC_TOT) +
                     (0.8f / 3.0f) * (fs / ((float)NR * (float)NR));
        }
    }
}

extern "C" void kernel_launch(void* const* d_in, const int* in_sizes, int n_in,
                              void* d_out, int out_size, void* d_ws, size_t ws_size,
                              hipStream_t stream) {
    unsigned* cnt  = (unsigned*)d_ws;
    float* msep    = (float*)((char*)d_ws + WS_MSEP_OFF);
    float* featp   = (float*)((char*)d_ws + WS_FEATP_OFF);
    float* sqn     = (float*)((char*)d_ws + WS_SQN_OFF);
    u8* q8         = (u8*)((char*)d_ws + WS_FP8_OFF);

    prep_mse_kernel<<<dim3(1024, 8), 256, 0, stream>>>(
        (const float*)d_in[2], (const float*)d_in[3], (const float*)d_in[4],
        (const float*)d_in[5], (const float*)d_in[6], (const float*)d_in[7],
        (const float4*)d_in[0], (const float4*)d_in[1], q8, sqn, msep, cnt);

    gram_loss_kernel<<<dim3(NTRI, 3), 256, 0, stream>>>(
        q8, sqn, featp, msep, cnt, (float*)d_out);
}